// Round 18
// baseline (449.188 us; speedup 1.0000x reference)
//
#include <hip/hip_runtime.h>
#include <hip/hip_cooperative_groups.h>
#include <hip/hip_bf16.h>
#include <cstdint>
#include <cstddef>

namespace cg = cooperative_groups;

#define B_  2
#define Q_  256
#define KL  2048
#define D_  256
#define H_  8
#define HD_ 32
#define CH_ 256

typedef _Float16 f16;
typedef __fp16 fp16x2 __attribute__((ext_vector_type(2)));
typedef _Float16 f16x8 __attribute__((ext_vector_type(8)));
typedef unsigned short ushortv4 __attribute__((ext_vector_type(4)));
typedef unsigned int uintv4 __attribute__((ext_vector_type(4)));
typedef float f32x4 __attribute__((ext_vector_type(4)));

union UH  { fp16x2 h; unsigned int u; };
union UH8 { f16x8 h; unsigned int u[4]; };

__device__ __forceinline__ unsigned int pkrtz(float a, float b) {
  UH r; r.h = __builtin_amdgcn_cvt_pkrtz(a, b); return r.u;
}
__device__ __forceinline__ unsigned short f16bits(float a) {
  return (unsigned short)(pkrtz(a, 0.f) & 0xffffu);
}
__device__ __forceinline__ float h2f(unsigned short u) {
  __fp16 h = *(__fp16*)&u;
  return (float)h;
}
__device__ __forceinline__ unsigned int pk_fma(unsigned int a, unsigned int b,
                                               unsigned int c) {
  unsigned int d;
  asm("v_pk_fma_f16 %0, %1, %2, %3" : "=v"(d) : "v"(a), "v"(b), "v"(c));
  return d;
}
__device__ __forceinline__ unsigned int pk_max0(unsigned int a) {
  unsigned int d;
  asm("v_pk_max_f16 %0, %1, %2" : "=v"(d) : "v"(a), "v"(0u));
  return d;
}

struct ShPrep { float rows[2][16][257]; };
struct ShCpb  {
  unsigned int w1xs[128], w1ys[128], b1ps[128];
  unsigned short w2h[H_][264];
};
struct ShAttn {
  unsigned short Plds[16][16][128];
  float wredM[16][16];
  float wredS[16][16];
  float pacc[16][16][33];
};
union ShAll { ShPrep prep; ShCpb cpb; ShAttn attn; };

__global__ __launch_bounds__(1024, 4) void mega(
    const float* __restrict__ ent, const float* __restrict__ img,
    const float* __restrict__ rd,
    const float* __restrict__ Wq, const float* __restrict__ bq,
    const float* __restrict__ Wkv, const float* __restrict__ bkv,
    const float* __restrict__ W1, const float* __restrict__ b1,
    const float* __restrict__ W2,
    const float* __restrict__ Wo, const float* __restrict__ bo,
    float* __restrict__ out,
    unsigned short* __restrict__ entS, unsigned short* __restrict__ imgS,
    unsigned short* __restrict__ WqS, unsigned short* __restrict__ WkvS,
    unsigned short* __restrict__ WoS,
    unsigned short* __restrict__ cpb4, unsigned short* __restrict__ qpf,
    unsigned short* __restrict__ kps, unsigned short* __restrict__ vt,
    unsigned short* __restrict__ ctxb) {
  cg::grid_group grid = cg::this_grid();
  __shared__ ShAll sh;
  int blk = blockIdx.x, t = threadIdx.x;
  const float scale = 0.17677669529663687f;  // 1/sqrt(32)

  // ================= phase 0: prep (fp32 -> f16 fragment layouts) ==========
  {
    int half = t >> 9, tl = t & 511;
    int tile = blk + half * 256;
    bool act = tile < 352;
    const float* src = nullptr;
    unsigned short* dst = nullptr;
    if (act) {
      if (tile < 32)       { src = ent + (size_t)tile * 16 * D_;          dst = entS + (size_t)tile * 4096; }
      else if (tile < 288) { int k = tile - 32;  src = img + (size_t)k * 16 * D_; dst = imgS + (size_t)k * 4096; }
      else if (tile < 304) { int k = tile - 288; src = Wq  + (size_t)k * 16 * D_; dst = WqS  + (size_t)k * 4096; }
      else if (tile < 336) { int k = tile - 304; src = Wkv + (size_t)k * 16 * D_; dst = WkvS + (size_t)k * 4096; }
      else                 { int k = tile - 336; src = Wo  + (size_t)k * 16 * D_; dst = WoS  + (size_t)k * 4096; }
      int rr = tl >> 5, c0 = (tl & 31) * 8;
      float4 a = *(const float4*)(src + rr * D_ + c0);
      float4 b = *(const float4*)(src + rr * D_ + c0 + 4);
      float (*rows)[257] = sh.prep.rows[half];
      rows[rr][c0 + 0] = a.x; rows[rr][c0 + 1] = a.y;
      rows[rr][c0 + 2] = a.z; rows[rr][c0 + 3] = a.w;
      rows[rr][c0 + 4] = b.x; rows[rr][c0 + 5] = b.y;
      rows[rr][c0 + 6] = b.z; rows[rr][c0 + 7] = b.w;
    }
    __syncthreads();
    if (act) {
      int s = tl >> 6, l = tl & 63, r = l & 15, g = l >> 4;
      const float* rp = &sh.prep.rows[half][r][s * 32 + g * 8];
      UH8 u;
#pragma unroll
      for (int m = 0; m < 4; ++m) u.u[m] = pkrtz(rp[2 * m], rp[2 * m + 1]);
      ((f16x8*)dst)[s * 64 + l] = u.h;
    }
  }
  __threadfence();
  grid.sync();

  // ================= phase 1: cpb (z-MLP + W2 MFMA) || q/kv projections ====
  {
    if (t < 128) {
      float4 wr = *(const float4*)(W1 + 4 * t);
      sh.cpb.w1xs[t] = pkrtz(wr.x, wr.z);
      sh.cpb.w1ys[t] = pkrtz(wr.y, wr.w);
      float2 bb = *(const float2*)(b1 + 2 * t);
      sh.cpb.b1ps[t] = pkrtz(bb.x, bb.y);
    }
    if (t < 512) {
      int h = t >> 6, c0 = (t & 63) * 4;
      float4 wv = *(const float4*)(W2 + h * CH_ + c0);
      sh.cpb.w2h[h][c0 + 0] = f16bits(wv.x);
      sh.cpb.w2h[h][c0 + 1] = f16bits(wv.y);
      sh.cpb.w2h[h][c0 + 2] = f16bits(wv.z);
      sh.cpb.w2h[h][c0 + 3] = f16bits(wv.w);
    }
    __syncthreads();
    int grp = (blk << 2) | (t >> 8);
    int tl = t & 255;
    int l = tl & 63, w = tl >> 6;

    // ---- cpb sub-blocks ----
    for (int sb = grp; sb < 2048; sb += 1024) {
      int kcg = sb & 15, qg = (sb >> 4) & 63, b = sb >> 10;
      int hp = l & 15, g = l >> 4, hq = hp & 7;
      int k0 = kcg * 128 + w * 32;
      int kt0 = k0 >> 4;

      unsigned int x2[4][2], y2[4][2];
#pragma unroll
      for (int q = 0; q < 4; ++q) {
        const float* rdb = rd + ((size_t)(b * Q_ + qg * 4 + q) * KL) * 2;
#pragma unroll
        for (int r = 0; r < 2; ++r) {
          float2 p = *(const float2*)(rdb + (k0 + r * 16 + hp) * 2);
          x2[q][r] = pkrtz(p.x, p.x);
          y2[q][r] = pkrtz(p.y, p.y);
        }
      }
      f32x4 acc[4][2];
#pragma unroll
      for (int q = 0; q < 4; ++q)
#pragma unroll
        for (int r = 0; r < 2; ++r) acc[q][r] = (f32x4){0.f, 0.f, 0.f, 0.f};

#pragma unroll
      for (int s = 0; s < 8; ++s) {
        int pidx = g * 4 + 16 * s;
        uintv4 wx = *(const uintv4*)&sh.cpb.w1xs[pidx];
        uintv4 wy = *(const uintv4*)&sh.cpb.w1ys[pidx];
        uintv4 bp = *(const uintv4*)&sh.cpb.b1ps[pidx];
        f16x8 w2f = *(const f16x8*)&sh.cpb.w2h[hq][g * 8 + 32 * s];
#pragma unroll
        for (int q = 0; q < 4; ++q)
#pragma unroll
          for (int r = 0; r < 2; ++r) {
            UH8 az;
#pragma unroll
            for (int m = 0; m < 4; ++m)
              az.u[m] = pk_max0(pk_fma(x2[q][r], wx[m], pk_fma(y2[q][r], wy[m], bp[m])));
            acc[q][r] = __builtin_amdgcn_mfma_f32_16x16x32_f16(az.h, w2f, acc[q][r], 0, 0, 0);
          }
      }
      if (hp < 8) {
#pragma unroll
        for (int q = 0; q < 4; ++q) {
          int qrow = qg * 4 + q;
          int qt = qrow >> 4, qc = qrow & 15;
#pragma unroll
          for (int r = 0; r < 2; ++r) {
            size_t T = ((size_t)(b * 8 + hp) * 128 + kt0 + r) * 16 + qt;
            uint2 pk;
            pk.x = pkrtz(acc[q][r][0], acc[q][r][1]);
            pk.y = pkrtz(acc[q][r][2], acc[q][r][3]);
            *(uint2*)(cpb4 + T * 256 + (g * 16 + qc) * 4) = pk;
          }
        }
      }
    }

    // ---- projection sub-blocks ----
    for (int sb = grp; sb < 1088; sb += 1024) {
      int r = l & 15, g = l >> 4;
      if (sb < 64) {
        int nt = sb & 3, mg = sb >> 2;
        const f16x8* A = (const f16x8*)entS;
        const f16x8* Bf = (const f16x8*)WqS;
        int tB = nt * 4 + w;
        f16x8 bf[8], av[8];
#pragma unroll
        for (int s = 0; s < 8; ++s) bf[s] = Bf[(tB * 8 + s) * 64 + l];
#pragma unroll
        for (int s = 0; s < 8; ++s) av[s] = A[((mg * 2) * 8 + s) * 64 + l];
        f32x4 acc0 = {0.f, 0.f, 0.f, 0.f};
#pragma unroll
        for (int s = 0; s < 8; ++s)
          acc0 = __builtin_amdgcn_mfma_f32_16x16x32_f16(av[s], bf[s], acc0, 0, 0, 0);
#pragma unroll
        for (int s = 0; s < 8; ++s) av[s] = A[((mg * 2 + 1) * 8 + s) * 64 + l];
        f32x4 acc1 = {0.f, 0.f, 0.f, 0.f};
#pragma unroll
        for (int s = 0; s < 8; ++s)
          acc1 = __builtin_amdgcn_mfma_f32_16x16x32_f16(av[s], bf[s], acc1, 0, 0, 0);
        int n = nt * 64 + w * 16 + r;
        float bb = bq[n];
        int h = n >> 5, gq = (n >> 3) & 3, e = n & 7;
        int m0 = mg * 32;
#pragma unroll
        for (int half = 0; half < 2; ++half) {
          f32x4 ac = half ? acc1 : acc0;
#pragma unroll
          for (int rr = 0; rr < 4; ++rr) {
            int row = m0 + half * 16 + g * 4 + rr;
            int qt_g = row >> 4, rq = row & 15;
            qpf[((size_t)(qt_g * 8 + h)) * 512 + (gq * 16 + rq) * 8 + e] =
                f16bits((ac[rr] + bb) * scale);
          }
        }
      } else {
        int bid2 = sb - 64;
        int nt = bid2 & 7, mg = (bid2 >> 3) & 63, b = bid2 >> 9;
        const f16x8* A = (const f16x8*)imgS;
        const f16x8* Bf = (const f16x8*)WkvS;
        int tB = nt * 4 + w;
        int tA0 = b * 128 + mg * 2;
        f16x8 bf[8], av[8];
#pragma unroll
        for (int s = 0; s < 8; ++s) bf[s] = Bf[(tB * 8 + s) * 64 + l];
#pragma unroll
        for (int s = 0; s < 8; ++s) av[s] = A[(tA0 * 8 + s) * 64 + l];
        f32x4 acc0 = {0.f, 0.f, 0.f, 0.f};
#pragma unroll
        for (int s = 0; s < 8; ++s)
          acc0 = __builtin_amdgcn_mfma_f32_16x16x32_f16(av[s], bf[s], acc0, 0, 0, 0);
#pragma unroll
        for (int s = 0; s < 8; ++s) av[s] = A[((tA0 + 1) * 8 + s) * 64 + l];
        f32x4 acc1 = {0.f, 0.f, 0.f, 0.f};
#pragma unroll
        for (int s = 0; s < 8; ++s)
          acc1 = __builtin_amdgcn_mfma_f32_16x16x32_f16(av[s], bf[s], acc1, 0, 0, 0);
        int n = nt * 64 + w * 16 + r;
        float bb = bkv[n];
#pragma unroll
        for (int mi = 0; mi < 2; ++mi) {
          f32x4 ac = (mi == 0) ? acc0 : acc1;
          int mt = mg * 2 + mi;
          if (n < 256) {
            int s2 = n >> 5, gg = (n >> 3) & 3, e = n & 7;
            size_t base = ((size_t)((b * 128 + mt) * 8 + s2) * 64 + gg * 16) * 8 + e;
#pragma unroll
            for (int rr = 0; rr < 4; ++rr)
              kps[base + (size_t)(g * 4 + rr) * 8] = f16bits(ac[rr] + bb);
          } else {
            int c = n - 256, h = c >> 5, dd = c & 31;
            ushortv4 p;
#pragma unroll
            for (int rr = 0; rr < 4; ++rr) p[rr] = f16bits(ac[rr] + bb);
            *(ushortv4*)(vt + ((size_t)(b * H_ + h) * HD_ + dd) * KL + mt * 16 + g * 4) = p;
          }
        }
      }
    }
  }
  __threadfence();
  grid.sync();

  // ================= phase 2: attn (dense QK + cpb-C + softmax + PV) =======
  {
    int qt = blk & 15, bh = blk >> 4;
    int b = bh >> 3, h = bh & 7;
    int w = t >> 6, l = t & 63;
    int qq = l & 15, g = l >> 4;

    UH8 qB;
    {
      const unsigned int* qpu = (const unsigned int*)qpf;
      uintv4 qv = *(const uintv4*)(qpu + ((size_t)((b * 16 + qt) * 8 + h)) * 256 + l * 4);
#pragma unroll
      for (int m = 0; m < 4; ++m) qB.u[m] = qv[m];
    }

    const f16x8* ka = (const f16x8*)kps + ((size_t)(b * 128) * 8) * 64 + l;
    const unsigned short* cb = cpb4 + ((size_t)bh * 128 * 16 + qt) * 256 + l * 4;
    f32x4 S[8];
#pragma unroll
    for (int i = 0; i < 8; ++i) {
      int kt = w * 8 + i;
      uint2 c2 = *(const uint2*)(cb + (size_t)kt * 4096);
      f32x4 C;
      C[0] = h2f((unsigned short)(c2.x & 0xffff));
      C[1] = h2f((unsigned short)(c2.x >> 16));
      C[2] = h2f((unsigned short)(c2.y & 0xffff));
      C[3] = h2f((unsigned short)(c2.y >> 16));
      f16x8 af = ka[((size_t)kt * 8 + h) * 64];
      S[i] = __builtin_amdgcn_mfma_f32_16x16x32_f16(af, qB.h, C, 0, 0, 0);
    }

    float m = -3.0e38f;
#pragma unroll
    for (int i = 0; i < 8; ++i)
#pragma unroll
      for (int rr = 0; rr < 4; ++rr) m = fmaxf(m, S[i][rr]);
    m = fmaxf(m, __shfl_xor(m, 16));
    m = fmaxf(m, __shfl_xor(m, 32));
    if (l < 16) sh.attn.wredM[w][l] = m;
    __syncthreads();
    float M = sh.attn.wredM[0][qq];
#pragma unroll
    for (int wv = 1; wv < 16; ++wv) M = fmaxf(M, sh.attn.wredM[wv][qq]);

    float ss = 0.f;
    char* prow = (char*)&sh.attn.Plds[w][qq][0];
    int xr = (qq & 7) << 4;
#pragma unroll
    for (int i = 0; i < 8; ++i) {
      float p0 = __expf(S[i][0] - M);
      float p1 = __expf(S[i][1] - M);
      float p2 = __expf(S[i][2] - M);
      float p3 = __expf(S[i][3] - M);
      ss += (p0 + p1) + (p2 + p3);
      uint2 pk;
      pk.x = pkrtz(p0, p1);
      pk.y = pkrtz(p2, p3);
      *(uint2*)(prow + ((i * 32 + g * 8) ^ xr)) = pk;
    }
    ss += __shfl_xor(ss, 16);
    ss += __shfl_xor(ss, 32);
    if (l < 16) sh.attn.wredS[w][l] = ss;

    const unsigned short* vb0 = vt + ((size_t)bh * HD_ + qq) * KL + w * 128 + g * 8;
    const unsigned short* vb1 = vb0 + (size_t)16 * KL;
    f32x4 a0 = {0.f, 0.f, 0.f, 0.f}, a1 = {0.f, 0.f, 0.f, 0.f};
#pragma unroll
    for (int cw = 0; cw < 4; ++cw) {
      f16x8 pa = *(const f16x8*)(prow + ((cw * 64 + g * 16) ^ xr));
      f16x8 v0 = *(const f16x8*)(vb0 + cw * 32);
      f16x8 v1 = *(const f16x8*)(vb1 + cw * 32);
      a0 = __builtin_amdgcn_mfma_f32_16x16x32_f16(pa, v0, a0, 0, 0, 0);
      a1 = __builtin_amdgcn_mfma_f32_16x16x32_f16(pa, v1, a1, 0, 0, 0);
    }
#pragma unroll
    for (int rr = 0; rr < 4; ++rr) {
      sh.attn.pacc[w][g * 4 + rr][qq] = a0[rr];
      sh.attn.pacc[w][g * 4 + rr][qq + 16] = a1[rr];
    }
    __syncthreads();

    if (t < 512) {
      int qo = t >> 5, dd = t & 31;
      float sum = 0.f, st = 0.f;
#pragma unroll
      for (int wv = 0; wv < 16; ++wv) {
        sum += sh.attn.pacc[wv][qo][dd];
        st += sh.attn.wredS[wv][qo];
      }
      ctxb[((size_t)b * Q_ + qt * 16 + qo) * D_ + h * HD_ + dd] = f16bits(sum / st);
    }
  }
  __threadfence();
  grid.sync();

  // ================= phase 3: out projection ===============================
  {
    int grp = (blk << 2) | (t >> 8);
    if (grp < 128) {
      int tl = t & 255;
      int l = tl & 63, w = tl >> 6;
      int nt = grp & 3, mt = grp >> 2;
      int m0 = mt * 16;
      int r = l & 15, g = l >> 4;
      const unsigned short* arow = ctxb + (size_t)(m0 + r) * D_;
      int tB = nt * 4 + w;
      f16x8 af[8], bf[8];
#pragma unroll
      for (int s = 0; s < 8; ++s) {
        af[s] = *(const f16x8*)(arow + s * 32 + g * 8);
        bf[s] = ((const f16x8*)WoS)[(tB * 8 + s) * 64 + l];
      }
      f32x4 acc = {0.f, 0.f, 0.f, 0.f};
#pragma unroll
      for (int s = 0; s < 8; ++s)
        acc = __builtin_amdgcn_mfma_f32_16x16x32_f16(af[s], bf[s], acc, 0, 0, 0);
      int n = nt * 64 + w * 16 + r;
      float bb = bo[n];
#pragma unroll
      for (int rr = 0; rr < 4; ++rr)
        out[(size_t)(m0 + g * 4 + rr) * D_ + n] = acc[rr] + bb;
    }
  }
}

extern "C" void kernel_launch(void* const* d_in, const int* in_sizes, int n_in,
                              void* d_out, int out_size, void* d_ws, size_t ws_size,
                              hipStream_t stream) {
  const float* ent  = (const float*)d_in[0];
  const float* img  = (const float*)d_in[1];
  const float* rd   = (const float*)d_in[2];
  const float* Wq   = (const float*)d_in[3];
  const float* bq   = (const float*)d_in[4];
  const float* Wkv  = (const float*)d_in[5];
  const float* bkv  = (const float*)d_in[6];
  const float* W1   = (const float*)d_in[7];
  const float* b1   = (const float*)d_in[8];
  const float* W2   = (const float*)d_in[9];
  const float* b2   = (const float*)d_in[10];
  const float* Wo   = (const float*)d_in[11];
  const float* bo   = (const float*)d_in[12];
  float* out = (float*)d_out;
  (void)b2;  // cancels in softmax (constant per row)

  char* ws = (char*)d_ws;
  unsigned short* kps   = (unsigned short*)(ws + 0);         // 2,097,152 f16 swizzled K
  unsigned short* vt    = (unsigned short*)(ws + 2097152);   // 2,097,152 f16 [b][h][dd][k]
  unsigned short* cpb4  = (unsigned short*)(ws + 4194304);   // 16,777,216 f16 cpb fragments
  unsigned short* ctxb  = (unsigned short*)(ws + 20971520);  //   262,144 f16 [b][q][c]
  unsigned short* qpf   = (unsigned short*)(ws + 21233664);  //   262,144 f16 q fragments
  unsigned short* entS  = (unsigned short*)(ws + 21495808);  //   262,144 f16 frag
  unsigned short* imgS  = (unsigned short*)(ws + 21757952);  // 2,097,152 f16 frag
  unsigned short* WqS   = (unsigned short*)(ws + 23855104);  //   131,072 f16 frag
  unsigned short* WkvS  = (unsigned short*)(ws + 23986176);  //   262,144 f16 frag
  unsigned short* WoS   = (unsigned short*)(ws + 24248320);  //   131,072 f16 frag

  void* args[] = {
      (void*)&ent, (void*)&img, (void*)&rd,
      (void*)&Wq, (void*)&bq, (void*)&Wkv, (void*)&bkv,
      (void*)&W1, (void*)&b1, (void*)&W2,
      (void*)&Wo, (void*)&bo, (void*)&out,
      (void*)&entS, (void*)&imgS, (void*)&WqS, (void*)&WkvS, (void*)&WoS,
      (void*)&cpb4, (void*)&qpf, (void*)&kps, (void*)&vt, (void*)&ctxb};
  hipLaunchCooperativeKernel((const void*)mega, dim3(256), dim3(1024), args, 0,
                             stream);
}

// Round 19
// 53.446 us; speedup vs baseline: 8.4045x; 8.4045x over previous
//
#include <hip/hip_runtime.h>
#include <hip/hip_bf16.h>
#include <cstdint>
#include <cstddef>

#define B_  2
#define Q_  256
#define KL  2048
#define D_  256
#define H_  8
#define HD_ 32
#define CH_ 256

typedef _Float16 f16;
typedef __fp16 fp16x2 __attribute__((ext_vector_type(2)));
typedef _Float16 f16x8 __attribute__((ext_vector_type(8)));
typedef unsigned short ushortv4 __attribute__((ext_vector_type(4)));
typedef unsigned int uintv4 __attribute__((ext_vector_type(4)));
typedef float f32x4 __attribute__((ext_vector_type(4)));

union UH  { fp16x2 h; unsigned int u; };
union UH8 { f16x8 h; unsigned int u[4]; };

__device__ __forceinline__ unsigned int pkrtz(float a, float b) {
  UH r; r.h = __builtin_amdgcn_cvt_pkrtz(a, b); return r.u;
}
__device__ __forceinline__ unsigned short f16bits(float a) {
  return (unsigned short)(pkrtz(a, 0.f) & 0xffffu);
}
__device__ __forceinline__ float h2f(unsigned short u) {
  __fp16 h = *(__fp16*)&u;
  return (float)h;
}
__device__ __forceinline__ unsigned int pk_fma(unsigned int a, unsigned int b,
                                               unsigned int c) {
  unsigned int d;
  asm("v_pk_fma_f16 %0, %1, %2, %3" : "=v"(d) : "v"(a), "v"(b), "v"(c));
  return d;
}
__device__ __forceinline__ unsigned int pk_max0(unsigned int a) {
  unsigned int d;
  asm("v_pk_max_f16 %0, %1, %2" : "=v"(d) : "v"(a), "v"(0u));
  return d;
}

// ---------- prep: fp32 row-major -> f16 MFMA-fragment layout; also zeroes out
// tiles: [0,32) ent | [32,288) img | [288,304) Wq | [304,336) Wkv
__global__ __launch_bounds__(512) void prep(
    const float* __restrict__ ent, const float* __restrict__ img,
    const float* __restrict__ Wq, const float* __restrict__ Wkv,
    unsigned short* __restrict__ entS, unsigned short* __restrict__ imgS,
    unsigned short* __restrict__ WqS, unsigned short* __restrict__ WkvS,
    float* __restrict__ out) {
  int bid = blockIdx.x, t = threadIdx.x;
  {
    int gi = bid * 512 + t;
    if (gi < B_ * Q_ * D_) out[gi] = 0.f;
  }
  const float* src;
  unsigned short* dst;
  if (bid < 32)       { src = ent + (size_t)bid * 16 * D_;          dst = entS + (size_t)bid * 4096; }
  else if (bid < 288) { int k = bid - 32;  src = img + (size_t)k * 16 * D_; dst = imgS + (size_t)k * 4096; }
  else if (bid < 304) { int k = bid - 288; src = Wq  + (size_t)k * 16 * D_; dst = WqS  + (size_t)k * 4096; }
  else                { int k = bid - 304; src = Wkv + (size_t)k * 16 * D_; dst = WkvS + (size_t)k * 4096; }
  __shared__ float rows[16][257];
  {
    int rr = t >> 5, c0 = (t & 31) * 8;
    float4 a = *(const float4*)(src + rr * D_ + c0);
    float4 b = *(const float4*)(src + rr * D_ + c0 + 4);
    rows[rr][c0 + 0] = a.x; rows[rr][c0 + 1] = a.y;
    rows[rr][c0 + 2] = a.z; rows[rr][c0 + 3] = a.w;
    rows[rr][c0 + 4] = b.x; rows[rr][c0 + 5] = b.y;
    rows[rr][c0 + 6] = b.z; rows[rr][c0 + 7] = b.w;
  }
  __syncthreads();
  int s = t >> 6, l = t & 63, r = l & 15, g = l >> 4;
  const float* rp = &rows[r][s * 32 + g * 8];
  UH8 u;
#pragma unroll
  for (int m = 0; m < 4; ++m) u.u[m] = pkrtz(rp[2 * m], rp[2 * m + 1]);
  ((f16x8*)dst)[s * 64 + l] = u.h;
}

// ---------- fused mid-kernel: blocks [0,2048) = cpb; [2048,3136) = q/kv proj
__global__ __launch_bounds__(256) void mid(
    const float* __restrict__ rd, const float* __restrict__ W1,
    const float* __restrict__ b1, const float* __restrict__ W2,
    unsigned short* __restrict__ cpb4,
    const unsigned short* __restrict__ entS, const unsigned short* __restrict__ WqS,
    const float* __restrict__ bq, unsigned short* __restrict__ qpf,
    const unsigned short* __restrict__ imgS, const unsigned short* __restrict__ WkvS,
    const float* __restrict__ bkv, unsigned short* __restrict__ kps,
    unsigned short* __restrict__ vt) {
  int bid0 = blockIdx.x;
  int t = threadIdx.x, w = t >> 6, l = t & 63;
  const float scale = 0.17677669529663687f;  // 1/sqrt(32)
  if (bid0 < 2048) {
    int gid = bid0;
    int kcg = gid & 15, qg = (gid >> 4) & 63, b = gid >> 10;
    __shared__ unsigned int w1xs[128], w1ys[128], b1ps[128];
    __shared__ unsigned short w2h[H_][264];
    if (t < 128) {
      float4 wr = *(const float4*)(W1 + 4 * t);
      w1xs[t] = pkrtz(wr.x, wr.z);
      w1ys[t] = pkrtz(wr.y, wr.w);
      float2 bb = *(const float2*)(b1 + 2 * t);
      b1ps[t] = pkrtz(bb.x, bb.y);
    }
#pragma unroll
    for (int i = 0; i < 2; ++i) {
      int idx = t + i * 256;
      int h = idx >> 6, c0 = (idx & 63) * 4;
      float4 wv = *(const float4*)(W2 + h * CH_ + c0);
      w2h[h][c0 + 0] = f16bits(wv.x);
      w2h[h][c0 + 1] = f16bits(wv.y);
      w2h[h][c0 + 2] = f16bits(wv.z);
      w2h[h][c0 + 3] = f16bits(wv.w);
    }
    __syncthreads();

    int hp = l & 15, g = l >> 4;
    int k0 = kcg * 128 + w * 32;
    int kt0 = k0 >> 4;

    unsigned int x2[4][2], y2[4][2];
#pragma unroll
    for (int q = 0; q < 4; ++q) {
      const float* rdb = rd + ((size_t)(b * Q_ + qg * 4 + q) * KL) * 2;
#pragma unroll
      for (int r = 0; r < 2; ++r) {
        float2 p = *(const float2*)(rdb + (k0 + r * 16 + hp) * 2);
        x2[q][r] = pkrtz(p.x, p.x);
        y2[q][r] = pkrtz(p.y, p.y);
      }
    }

    f32x4 acc[4][2];
#pragma unroll
    for (int q = 0; q < 4; ++q)
#pragma unroll
      for (int r = 0; r < 2; ++r) acc[q][r] = (f32x4){0.f, 0.f, 0.f, 0.f};

    int hq = hp & 7;
#pragma unroll
    for (int s = 0; s < 8; ++s) {
      int pidx = g * 4 + 16 * s;
      uintv4 wx = *(const uintv4*)&w1xs[pidx];
      uintv4 wy = *(const uintv4*)&w1ys[pidx];
      uintv4 bp = *(const uintv4*)&b1ps[pidx];
      f16x8 w2f = *(const f16x8*)&w2h[hq][g * 8 + 32 * s];
#pragma unroll
      for (int q = 0; q < 4; ++q)
#pragma unroll
        for (int r = 0; r < 2; ++r) {
          UH8 az;
#pragma unroll
          for (int m = 0; m < 4; ++m)
            az.u[m] = pk_max0(pk_fma(x2[q][r], wx[m], pk_fma(y2[q][r], wy[m], bp[m])));
          acc[q][r] = __builtin_amdgcn_mfma_f32_16x16x32_f16(az.h, w2f, acc[q][r], 0, 0, 0);
        }
    }

    if (hp < 8) {
#pragma unroll
      for (int q = 0; q < 4; ++q) {
        int qrow = qg * 4 + q;
        int qt = qrow >> 4, qc = qrow & 15;
#pragma unroll
        for (int r = 0; r < 2; ++r) {
          size_t T = ((size_t)(b * 8 + hp) * 128 + kt0 + r) * 16 + qt;
          uint2 pk;
          pk.x = pkrtz(acc[q][r][0], acc[q][r][1]);
          pk.y = pkrtz(acc[q][r][2], acc[q][r][3]);
          *(uint2*)(cpb4 + T * 256 + (g * 16 + qc) * 4) = pk;
        }
      }
    }
  } else {
    int bid = bid0 - 2048;
    int r = l & 15, g = l >> 4;
    if (bid < 64) {
      int nt = bid & 3, mg = bid >> 2;
      const f16x8* A = (const f16x8*)entS;
      const f16x8* Bf = (const f16x8*)WqS;
      int tA0 = mg * 2, tB = nt * 4 + w;
      f16x8 a0[8], a1[8], bf[8];
#pragma unroll
      for (int s = 0; s < 8; ++s) {
        a0[s] = A[(tA0 * 8 + s) * 64 + l];
        a1[s] = A[((tA0 + 1) * 8 + s) * 64 + l];
        bf[s] = Bf[(tB * 8 + s) * 64 + l];
      }
      f32x4 acc0 = {0.f, 0.f, 0.f, 0.f}, acc1 = {0.f, 0.f, 0.f, 0.f};
#pragma unroll
      for (int s = 0; s < 8; ++s) {
        acc0 = __builtin_amdgcn_mfma_f32_16x16x32_f16(a0[s], bf[s], acc0, 0, 0, 0);
        acc1 = __builtin_amdgcn_mfma_f32_16x16x32_f16(a1[s], bf[s], acc1, 0, 0, 0);
      }
      int n = nt * 64 + w * 16 + r;
      float bb = bq[n];
      int h = n >> 5, gq = (n >> 3) & 3, e = n & 7;
      int m0 = mg * 32;
#pragma unroll
      for (int half = 0; half < 2; ++half) {
        f32x4 ac = half ? acc1 : acc0;
#pragma unroll
        for (int rr = 0; rr < 4; ++rr) {
          int row = m0 + half * 16 + g * 4 + rr;
          int qt_g = row >> 4, rq = row & 15;
          qpf[((size_t)(qt_g * 8 + h)) * 512 + (gq * 16 + rq) * 8 + e] =
              f16bits((ac[rr] + bb) * scale);
        }
      }
    } else {
      int bid2 = bid - 64;
      int nt = bid2 & 7, mg = (bid2 >> 3) & 63, b = bid2 >> 9;
      const f16x8* A = (const f16x8*)imgS;
      const f16x8* Bf = (const f16x8*)WkvS;
      int tA0 = b * 128 + mg * 2, tB = nt * 4 + w;
      f16x8 a0[8], a1[8], bf[8];
#pragma unroll
      for (int s = 0; s < 8; ++s) {
        a0[s] = A[(tA0 * 8 + s) * 64 + l];
        a1[s] = A[((tA0 + 1) * 8 + s) * 64 + l];
        bf[s] = Bf[(tB * 8 + s) * 64 + l];
      }
      f32x4 acc0 = {0.f, 0.f, 0.f, 0.f}, acc1 = {0.f, 0.f, 0.f, 0.f};
#pragma unroll
      for (int s = 0; s < 8; ++s) {
        acc0 = __builtin_amdgcn_mfma_f32_16x16x32_f16(a0[s], bf[s], acc0, 0, 0, 0);
        acc1 = __builtin_amdgcn_mfma_f32_16x16x32_f16(a1[s], bf[s], acc1, 0, 0, 0);
      }
      int n = nt * 64 + w * 16 + r;
      float bb = bkv[n];
#pragma unroll
      for (int mi = 0; mi < 2; ++mi) {
        f32x4 ac = (mi == 0) ? acc0 : acc1;
        int mt = mg * 2 + mi;
        if (n < 256) {
          int s2 = n >> 5, gg = (n >> 3) & 3, e = n & 7;
          size_t base = ((size_t)((b * 128 + mt) * 8 + s2) * 64 + gg * 16) * 8 + e;
#pragma unroll
          for (int rr = 0; rr < 4; ++rr)
            kps[base + (size_t)(g * 4 + rr) * 8] = f16bits(ac[rr] + bb);
        } else {
          int c = n - 256, h = c >> 5, dd = c & 31;
          ushortv4 p;
#pragma unroll
          for (int rr = 0; rr < 4; ++rr) p[rr] = f16bits(ac[rr] + bb);
          *(ushortv4*)(vt + ((size_t)(b * H_ + h) * HD_ + dd) * KL + mt * 16 + g * 4) = p;
        }
      }
    }
  }
}

// ---------- attn + fused per-head out-projection (atomicAdd into out)
// block = ((b*8+h)*16 + qt), 1024 threads / 16 waves; wave -> 128 k
__global__ __launch_bounds__(1024) void attn(
    const unsigned short* __restrict__ qpf, const unsigned short* __restrict__ kps,
    const unsigned short* __restrict__ cpb4, const unsigned short* __restrict__ vt,
    const float* __restrict__ Wo, const float* __restrict__ bo,
    float* __restrict__ out) {
  int gid = blockIdx.x;
  int qt = gid & 15, bh = gid >> 4;
  int b = bh >> 3, h = bh & 7;
  int t = threadIdx.x, w = t >> 6, l = t & 63;
  int qq = l & 15, g = l >> 4;
  __shared__ unsigned short Plds[16][16][128];  // 64 KB, XOR-swizzled rows
  __shared__ float wredM[16][16];
  __shared__ float wredS[16][16];
  __shared__ float pacc[16][16][33];
  __shared__ unsigned short ctxh[16][32];       // f16 ctx tile (16q x 32dd)

  UH8 qB;
  {
    const unsigned int* qpu = (const unsigned int*)qpf;
    uintv4 qv = *(const uintv4*)(qpu + ((size_t)((b * 16 + qt) * 8 + h)) * 256 + l * 4);
#pragma unroll
    for (int m = 0; m < 4; ++m) qB.u[m] = qv[m];
  }

  const f16x8* ka = (const f16x8*)kps + ((size_t)(b * 128) * 8) * 64 + l;
  const unsigned short* cb = cpb4 + ((size_t)bh * 128 * 16 + qt) * 256 + l * 4;
  f32x4 S[8];
#pragma unroll
  for (int i = 0; i < 8; ++i) {
    int kt = w * 8 + i;
    uint2 c2 = *(const uint2*)(cb + (size_t)kt * 4096);
    f32x4 C;
    C[0] = h2f((unsigned short)(c2.x & 0xffff));
    C[1] = h2f((unsigned short)(c2.x >> 16));
    C[2] = h2f((unsigned short)(c2.y & 0xffff));
    C[3] = h2f((unsigned short)(c2.y >> 16));
    f16x8 af = ka[((size_t)kt * 8 + h) * 64];
    S[i] = __builtin_amdgcn_mfma_f32_16x16x32_f16(af, qB.h, C, 0, 0, 0);
  }

  float m = -3.0e38f;
#pragma unroll
  for (int i = 0; i < 8; ++i)
#pragma unroll
    for (int rr = 0; rr < 4; ++rr) m = fmaxf(m, S[i][rr]);
  m = fmaxf(m, __shfl_xor(m, 16));
  m = fmaxf(m, __shfl_xor(m, 32));
  if (l < 16) wredM[w][l] = m;
  __syncthreads();
  float M = wredM[0][qq];
#pragma unroll
  for (int wv = 1; wv < 16; ++wv) M = fmaxf(M, wredM[wv][qq]);

  float ss = 0.f;
  char* prow = (char*)&Plds[w][qq][0];
  int xr = (qq & 7) << 4;
#pragma unroll
  for (int i = 0; i < 8; ++i) {
    float p0 = __expf(S[i][0] - M);
    float p1 = __expf(S[i][1] - M);
    float p2 = __expf(S[i][2] - M);
    float p3 = __expf(S[i][3] - M);
    ss += (p0 + p1) + (p2 + p3);
    uint2 pk;
    pk.x = pkrtz(p0, p1);
    pk.y = pkrtz(p2, p3);
    *(uint2*)(prow + ((i * 32 + g * 8) ^ xr)) = pk;
  }
  ss += __shfl_xor(ss, 16);
  ss += __shfl_xor(ss, 32);
  if (l < 16) wredS[w][l] = ss;

  const unsigned short* vb0 = vt + ((size_t)bh * HD_ + qq) * KL + w * 128 + g * 8;
  const unsigned short* vb1 = vb0 + (size_t)16 * KL;
  f32x4 a0 = {0.f, 0.f, 0.f, 0.f}, a1 = {0.f, 0.f, 0.f, 0.f};
#pragma unroll
  for (int cw = 0; cw < 4; ++cw) {
    f16x8 pa = *(const f16x8*)(prow + ((cw * 64 + g * 16) ^ xr));
    f16x8 v0 = *(const f16x8*)(vb0 + cw * 32);
    f16x8 v1 = *(const f16x8*)(vb1 + cw * 32);
    a0 = __builtin_amdgcn_mfma_f32_16x16x32_f16(pa, v0, a0, 0, 0, 0);
    a1 = __builtin_amdgcn_mfma_f32_16x16x32_f16(pa, v1, a1, 0, 0, 0);
  }
#pragma unroll
  for (int rr = 0; rr < 4; ++rr) {
    pacc[w][g * 4 + rr][qq] = a0[rr];
    pacc[w][g * 4 + rr][qq + 16] = a1[rr];
  }
  __syncthreads();

  if (t < 512) {
    int qo = t >> 5, dd = t & 31;
    float sum = 0.f, st = 0.f;
#pragma unroll
    for (int wv = 0; wv < 16; ++wv) {
      sum += pacc[wv][qo][dd];
      st += wredS[wv][qo];
    }
    ctxh[qo][dd] = f16bits(sum / st);
  }
  __syncthreads();

  // per-head out-projection partial: wave w -> out cols [w*16, w*16+16)
  {
    int n = w * 16 + qq;
    const float* worow = Wo + (size_t)n * D_ + h * HD_ + g * 8;
    float4 wa = *(const float4*)(worow);
    float4 wb = *(const float4*)(worow + 4);
    UH8 bfr;
    bfr.u[0] = pkrtz(wa.x, wa.y);
    bfr.u[1] = pkrtz(wa.z, wa.w);
    bfr.u[2] = pkrtz(wb.x, wb.y);
    bfr.u[3] = pkrtz(wb.z, wb.w);
    f16x8 af = *(const f16x8*)&ctxh[qq][g * 8];
    f32x4 acc = {0.f, 0.f, 0.f, 0.f};
    acc = __builtin_amdgcn_mfma_f32_16x16x32_f16(af, bfr.h, acc, 0, 0, 0);
    float bb = (h == 0) ? bo[n] : 0.f;
#pragma unroll
    for (int rr = 0; rr < 4; ++rr) {
      int qrow = qt * 16 + g * 4 + rr;
      atomicAdd(&out[((size_t)(b * Q_ + qrow)) * D_ + n], acc[rr] + bb * 0.25f);
    }
  }
}

extern "C" void kernel_launch(void* const* d_in, const int* in_sizes, int n_in,
                              void* d_out, int out_size, void* d_ws, size_t ws_size,
                              hipStream_t stream) {
  const float* ent  = (const float*)d_in[0];
  const float* img  = (const float*)d_in[1];
  const float* rd   = (const float*)d_in[2];
  const float* Wq   = (const float*)d_in[3];
  const float* bq   = (const float*)d_in[4];
  const float* Wkv  = (const float*)d_in[5];
  const float* bkv  = (const float*)d_in[6];
  const float* W1   = (const float*)d_in[7];
  const float* b1   = (const float*)d_in[8];
  const float* W2   = (const float*)d_in[9];
  const float* b2   = (const float*)d_in[10];
  const float* Wo   = (const float*)d_in[11];
  const float* bo   = (const float*)d_in[12];
  float* out = (float*)d_out;
  (void)b2;  // cancels in softmax (constant per row)

  char* ws = (char*)d_ws;
  unsigned short* kps   = (unsigned short*)(ws + 0);         // 2,097,152 f16 swizzled K
  unsigned short* vt    = (unsigned short*)(ws + 2097152);   // 2,097,152 f16 [b][h][dd][k]
  unsigned short* cpb4  = (unsigned short*)(ws + 4194304);   // 16,777,216 f16 cpb fragments
  unsigned short* qpf   = (unsigned short*)(ws + 20971520);  //   262,144 f16 q fragments
  unsigned short* entS  = (unsigned short*)(ws + 21233664);  //   262,144 f16 frag
  unsigned short* imgS  = (unsigned short*)(ws + 21495808);  // 2,097,152 f16 frag
  unsigned short* WqS   = (unsigned short*)(ws + 23592960);  //   131,072 f16 frag
  unsigned short* WkvS  = (unsigned short*)(ws + 23724032);  //   262,144 f16 frag

  prep<<<dim3(336), dim3(512), 0, stream>>>(ent, img, Wq, Wkv,
                                            entS, imgS, WqS, WkvS, out);
  mid<<<dim3(2048 + 64 + 1024), dim3(256), 0, stream>>>(
      rd, W1, b1, W2, cpb4, entS, WqS, bq, qpf, imgS, WkvS, bkv, kps, vt);
  attn<<<dim3(B_ * H_ * 16), dim3(1024), 0, stream>>>(qpf, kps, cpb4, vt,
                                                      Wo, bo, out);
}

// Round 20
// 51.511 us; speedup vs baseline: 8.7202x; 1.0376x over previous
//
#include <hip/hip_runtime.h>
#include <hip/hip_bf16.h>
#include <cstdint>
#include <cstddef>

#define B_  2
#define Q_  256
#define KL  2048
#define D_  256
#define H_  8
#define HD_ 32
#define CH_ 256

typedef _Float16 f16;
typedef __fp16 fp16x2 __attribute__((ext_vector_type(2)));
typedef _Float16 f16x8 __attribute__((ext_vector_type(8)));
typedef unsigned short ushortv4 __attribute__((ext_vector_type(4)));
typedef unsigned int uintv4 __attribute__((ext_vector_type(4)));
typedef float f32x4 __attribute__((ext_vector_type(4)));

union UH  { fp16x2 h; unsigned int u; };
union UH8 { f16x8 h; unsigned int u[4]; };

__device__ __forceinline__ unsigned int pkrtz(float a, float b) {
  UH r; r.h = __builtin_amdgcn_cvt_pkrtz(a, b); return r.u;
}
__device__ __forceinline__ unsigned short f16bits(float a) {
  return (unsigned short)(pkrtz(a, 0.f) & 0xffffu);
}
__device__ __forceinline__ float h2f(unsigned short u) {
  __fp16 h = *(__fp16*)&u;
  return (float)h;
}
__device__ __forceinline__ unsigned int pk_fma(unsigned int a, unsigned int b,
                                               unsigned int c) {
  unsigned int d;
  asm("v_pk_fma_f16 %0, %1, %2, %3" : "=v"(d) : "v"(a), "v"(b), "v"(c));
  return d;
}
__device__ __forceinline__ unsigned int pk_max0(unsigned int a) {
  unsigned int d;
  asm("v_pk_max_f16 %0, %1, %2" : "=v"(d) : "v"(a), "v"(0u));
  return d;
}

// ---------- prep: fp32 row-major -> f16 MFMA-fragment layout
__global__ __launch_bounds__(512) void prep(
    const float* __restrict__ ent, const float* __restrict__ img,
    const float* __restrict__ Wq, const float* __restrict__ Wkv,
    const float* __restrict__ Wo,
    unsigned short* __restrict__ entS, unsigned short* __restrict__ imgS,
    unsigned short* __restrict__ WqS, unsigned short* __restrict__ WkvS,
    unsigned short* __restrict__ WoS) {
  int bid = blockIdx.x, t = threadIdx.x;
  const float* src;
  unsigned short* dst;
  if (bid < 32)       { src = ent + (size_t)bid * 16 * D_;          dst = entS + (size_t)bid * 4096; }
  else if (bid < 288) { int k = bid - 32;  src = img + (size_t)k * 16 * D_; dst = imgS + (size_t)k * 4096; }
  else if (bid < 304) { int k = bid - 288; src = Wq  + (size_t)k * 16 * D_; dst = WqS  + (size_t)k * 4096; }
  else if (bid < 336) { int k = bid - 304; src = Wkv + (size_t)k * 16 * D_; dst = WkvS + (size_t)k * 4096; }
  else                { int k = bid - 336; src = Wo  + (size_t)k * 16 * D_; dst = WoS  + (size_t)k * 4096; }
  __shared__ float rows[16][257];
  {
    int rr = t >> 5, c0 = (t & 31) * 8;
    float4 a = *(const float4*)(src + rr * D_ + c0);
    float4 b = *(const float4*)(src + rr * D_ + c0 + 4);
    rows[rr][c0 + 0] = a.x; rows[rr][c0 + 1] = a.y;
    rows[rr][c0 + 2] = a.z; rows[rr][c0 + 3] = a.w;
    rows[rr][c0 + 4] = b.x; rows[rr][c0 + 5] = b.y;
    rows[rr][c0 + 6] = b.z; rows[rr][c0 + 7] = b.w;
  }
  __syncthreads();
  int s = t >> 6, l = t & 63, r = l & 15, g = l >> 4;
  const float* rp = &rows[r][s * 32 + g * 8];
  UH8 u;
#pragma unroll
  for (int m = 0; m < 4; ++m) u.u[m] = pkrtz(rp[2 * m], rp[2 * m + 1]);
  ((f16x8*)dst)[s * 64 + l] = u.h;
}

// ---------- fused mid-kernel: blocks [0,2048) = cpb; [2048,3136) = q/kv proj
__global__ __launch_bounds__(256) void mid(
    const float* __restrict__ rd, const float* __restrict__ W1,
    const float* __restrict__ b1, const float* __restrict__ W2,
    unsigned short* __restrict__ cpb4,
    const unsigned short* __restrict__ entS, const unsigned short* __restrict__ WqS,
    const float* __restrict__ bq, unsigned short* __restrict__ qpf,
    const unsigned short* __restrict__ imgS, const unsigned short* __restrict__ WkvS,
    const float* __restrict__ bkv, unsigned short* __restrict__ kps,
    unsigned short* __restrict__ vt) {
  int bid0 = blockIdx.x;
  int t = threadIdx.x, w = t >> 6, l = t & 63;
  const float scale = 0.17677669529663687f;  // 1/sqrt(32)
  if (bid0 < 2048) {
    // ---- cpb branch ----
    int gid = bid0;
    int kcg = gid & 15, qg = (gid >> 4) & 63, b = gid >> 10;
    __shared__ unsigned int w1xs[128], w1ys[128], b1ps[128];
    __shared__ unsigned short w2h[H_][264];
    if (t < 128) {
      float4 wr = *(const float4*)(W1 + 4 * t);
      w1xs[t] = pkrtz(wr.x, wr.z);
      w1ys[t] = pkrtz(wr.y, wr.w);
      float2 bb = *(const float2*)(b1 + 2 * t);
      b1ps[t] = pkrtz(bb.x, bb.y);
    }
#pragma unroll
    for (int i = 0; i < 2; ++i) {
      int idx = t + i * 256;
      int h = idx >> 6, c0 = (idx & 63) * 4;
      float4 wv = *(const float4*)(W2 + h * CH_ + c0);
      w2h[h][c0 + 0] = f16bits(wv.x);
      w2h[h][c0 + 1] = f16bits(wv.y);
      w2h[h][c0 + 2] = f16bits(wv.z);
      w2h[h][c0 + 3] = f16bits(wv.w);
    }
    __syncthreads();

    int hp = l & 15, g = l >> 4;
    int k0 = kcg * 128 + w * 32;
    int kt0 = k0 >> 4;

    unsigned int x2[4][2], y2[4][2];
#pragma unroll
    for (int q = 0; q < 4; ++q) {
      const float* rdb = rd + ((size_t)(b * Q_ + qg * 4 + q) * KL) * 2;
#pragma unroll
      for (int r = 0; r < 2; ++r) {
        float2 p = *(const float2*)(rdb + (k0 + r * 16 + hp) * 2);
        x2[q][r] = pkrtz(p.x, p.x);
        y2[q][r] = pkrtz(p.y, p.y);
      }
    }

    f32x4 acc[4][2];
#pragma unroll
    for (int q = 0; q < 4; ++q)
#pragma unroll
      for (int r = 0; r < 2; ++r) acc[q][r] = (f32x4){0.f, 0.f, 0.f, 0.f};

    int hq = hp & 7;
#pragma unroll
    for (int s = 0; s < 8; ++s) {
      int pidx = g * 4 + 16 * s;
      uintv4 wx = *(const uintv4*)&w1xs[pidx];
      uintv4 wy = *(const uintv4*)&w1ys[pidx];
      uintv4 bp = *(const uintv4*)&b1ps[pidx];
      f16x8 w2f = *(const f16x8*)&w2h[hq][g * 8 + 32 * s];
#pragma unroll
      for (int q = 0; q < 4; ++q)
#pragma unroll
        for (int r = 0; r < 2; ++r) {
          UH8 az;
#pragma unroll
          for (int m = 0; m < 4; ++m)
            az.u[m] = pk_max0(pk_fma(x2[q][r], wx[m], pk_fma(y2[q][r], wy[m], bp[m])));
          acc[q][r] = __builtin_amdgcn_mfma_f32_16x16x32_f16(az.h, w2f, acc[q][r], 0, 0, 0);
        }
    }

    if (hp < 8) {
#pragma unroll
      for (int q = 0; q < 4; ++q) {
        int qrow = qg * 4 + q;
        int qt = qrow >> 4, qc = qrow & 15;
#pragma unroll
        for (int r = 0; r < 2; ++r) {
          size_t T = ((size_t)(b * 8 + hp) * 128 + kt0 + r) * 16 + qt;
          uint2 pk;
          pk.x = pkrtz(acc[q][r][0], acc[q][r][1]);
          pk.y = pkrtz(acc[q][r][2], acc[q][r][3]);
          *(uint2*)(cpb4 + T * 256 + (g * 16 + qc) * 4) = pk;
        }
      }
    }
  } else {
    // ---- projection branch ----
    int bid = bid0 - 2048;
    int r = l & 15, g = l >> 4;
    if (bid < 64) {
      int nt = bid & 3, mg = bid >> 2;
      const f16x8* A = (const f16x8*)entS;
      const f16x8* Bf = (const f16x8*)WqS;
      int tA0 = mg * 2, tB = nt * 4 + w;
      f16x8 a0[8], a1[8], bf[8];
#pragma unroll
      for (int s = 0; s < 8; ++s) {
        a0[s] = A[(tA0 * 8 + s) * 64 + l];
        a1[s] = A[((tA0 + 1) * 8 + s) * 64 + l];
        bf[s] = Bf[(tB * 8 + s) * 64 + l];
      }
      f32x4 acc0 = {0.f, 0.f, 0.f, 0.f}, acc1 = {0.f, 0.f, 0.f, 0.f};
#pragma unroll
      for (int s = 0; s < 8; ++s) {
        acc0 = __builtin_amdgcn_mfma_f32_16x16x32_f16(a0[s], bf[s], acc0, 0, 0, 0);
        acc1 = __builtin_amdgcn_mfma_f32_16x16x32_f16(a1[s], bf[s], acc1, 0, 0, 0);
      }
      int n = nt * 64 + w * 16 + r;
      float bb = bq[n];
      int h = n >> 5, gq = (n >> 3) & 3, e = n & 7;
      int m0 = mg * 32;
#pragma unroll
      for (int half = 0; half < 2; ++half) {
        f32x4 ac = half ? acc1 : acc0;
#pragma unroll
        for (int rr = 0; rr < 4; ++rr) {
          int row = m0 + half * 16 + g * 4 + rr;
          int qt_g = row >> 4, rq = row & 15;
          qpf[((size_t)(qt_g * 8 + h)) * 512 + (gq * 16 + rq) * 8 + e] =
              f16bits((ac[rr] + bb) * scale);
        }
      }
    } else {
      int bid2 = bid - 64;
      int nt = bid2 & 7, mg = (bid2 >> 3) & 63, b = bid2 >> 9;
      const f16x8* A = (const f16x8*)imgS;
      const f16x8* Bf = (const f16x8*)WkvS;
      int tA0 = b * 128 + mg * 2, tB = nt * 4 + w;
      f16x8 a0[8], a1[8], bf[8];
#pragma unroll
      for (int s = 0; s < 8; ++s) {
        a0[s] = A[(tA0 * 8 + s) * 64 + l];
        a1[s] = A[((tA0 + 1) * 8 + s) * 64 + l];
        bf[s] = Bf[(tB * 8 + s) * 64 + l];
      }
      f32x4 acc0 = {0.f, 0.f, 0.f, 0.f}, acc1 = {0.f, 0.f, 0.f, 0.f};
#pragma unroll
      for (int s = 0; s < 8; ++s) {
        acc0 = __builtin_amdgcn_mfma_f32_16x16x32_f16(a0[s], bf[s], acc0, 0, 0, 0);
        acc1 = __builtin_amdgcn_mfma_f32_16x16x32_f16(a1[s], bf[s], acc1, 0, 0, 0);
      }
      int n = nt * 64 + w * 16 + r;
      float bb = bkv[n];
#pragma unroll
      for (int mi = 0; mi < 2; ++mi) {
        f32x4 ac = (mi == 0) ? acc0 : acc1;
        int mt = mg * 2 + mi;
        if (n < 256) {
          int s2 = n >> 5, gg = (n >> 3) & 3, e = n & 7;
          size_t base = ((size_t)((b * 128 + mt) * 8 + s2) * 64 + gg * 16) * 8 + e;
#pragma unroll
          for (int rr = 0; rr < 4; ++rr)
            kps[base + (size_t)(g * 4 + rr) * 8] = f16bits(ac[rr] + bb);
        } else {
          int c = n - 256, h = c >> 5, dd = c & 31;
          ushortv4 p;
#pragma unroll
          for (int rr = 0; rr < 4; ++rr) p[rr] = f16bits(ac[rr] + bb);
          *(ushortv4*)(vt + ((size_t)(b * H_ + h) * HD_ + dd) * KL + mt * 16 + g * 4) = p;
        }
      }
    }
  }
}

// ---------- attn: dense QK (+cpb as C) + exact softmax + PV
// block = ((b*8+h)*16 + qt), 1024 threads / 16 waves; wave -> 128 k
__global__ __launch_bounds__(1024) void attn(
    const unsigned short* __restrict__ qpf, const unsigned short* __restrict__ kps,
    const unsigned short* __restrict__ cpb4, const unsigned short* __restrict__ vt,
    unsigned short* __restrict__ ctxb) {
  int gid = blockIdx.x;
  int qt = gid & 15, bh = gid >> 4;
  int b = bh >> 3, h = bh & 7;
  int t = threadIdx.x, w = t >> 6, l = t & 63;
  int qq = l & 15, g = l >> 4;
  __shared__ unsigned short Plds[16][16][128];  // 64 KB, XOR-swizzled rows
  __shared__ float wredM[16][16];
  __shared__ float wredS[16][16];
  __shared__ float pacc[16][16][33];

  UH8 qB;
  {
    const unsigned int* qpu = (const unsigned int*)qpf;
    uintv4 qv = *(const uintv4*)(qpu + ((size_t)((b * 16 + qt) * 8 + h)) * 256 + l * 4);
#pragma unroll
    for (int m = 0; m < 4; ++m) qB.u[m] = qv[m];
  }

  const f16x8* ka = (const f16x8*)kps + ((size_t)(b * 128) * 8) * 64 + l;
  const unsigned short* cb = cpb4 + ((size_t)bh * 128 * 16 + qt) * 256 + l * 4;
  f32x4 S[8];
#pragma unroll
  for (int i = 0; i < 8; ++i) {
    int kt = w * 8 + i;
    uint2 c2 = *(const uint2*)(cb + (size_t)kt * 4096);
    f32x4 C;
    C[0] = h2f((unsigned short)(c2.x & 0xffff));
    C[1] = h2f((unsigned short)(c2.x >> 16));
    C[2] = h2f((unsigned short)(c2.y & 0xffff));
    C[3] = h2f((unsigned short)(c2.y >> 16));
    f16x8 af = ka[((size_t)kt * 8 + h) * 64];
    S[i] = __builtin_amdgcn_mfma_f32_16x16x32_f16(af, qB.h, C, 0, 0, 0);
  }

  float m = -3.0e38f;
#pragma unroll
  for (int i = 0; i < 8; ++i)
#pragma unroll
    for (int rr = 0; rr < 4; ++rr) m = fmaxf(m, S[i][rr]);
  m = fmaxf(m, __shfl_xor(m, 16));
  m = fmaxf(m, __shfl_xor(m, 32));
  if (l < 16) wredM[w][l] = m;
  __syncthreads();
  float M = wredM[0][qq];
#pragma unroll
  for (int wv = 1; wv < 16; ++wv) M = fmaxf(M, wredM[wv][qq]);

  float ss = 0.f;
  char* prow = (char*)&Plds[w][qq][0];
  int xr = (qq & 7) << 4;
#pragma unroll
  for (int i = 0; i < 8; ++i) {
    float p0 = __expf(S[i][0] - M);
    float p1 = __expf(S[i][1] - M);
    float p2 = __expf(S[i][2] - M);
    float p3 = __expf(S[i][3] - M);
    ss += (p0 + p1) + (p2 + p3);
    uint2 pk;
    pk.x = pkrtz(p0, p1);
    pk.y = pkrtz(p2, p3);
    *(uint2*)(prow + ((i * 32 + g * 8) ^ xr)) = pk;
  }
  ss += __shfl_xor(ss, 16);
  ss += __shfl_xor(ss, 32);
  if (l < 16) wredS[w][l] = ss;

  const unsigned short* vb0 = vt + ((size_t)bh * HD_ + qq) * KL + w * 128 + g * 8;
  const unsigned short* vb1 = vb0 + (size_t)16 * KL;
  f32x4 a0 = {0.f, 0.f, 0.f, 0.f}, a1 = {0.f, 0.f, 0.f, 0.f};
#pragma unroll
  for (int cw = 0; cw < 4; ++cw) {
    f16x8 pa = *(const f16x8*)(prow + ((cw * 64 + g * 16) ^ xr));
    f16x8 v0 = *(const f16x8*)(vb0 + cw * 32);
    f16x8 v1 = *(const f16x8*)(vb1 + cw * 32);
    a0 = __builtin_amdgcn_mfma_f32_16x16x32_f16(pa, v0, a0, 0, 0, 0);
    a1 = __builtin_amdgcn_mfma_f32_16x16x32_f16(pa, v1, a1, 0, 0, 0);
  }
#pragma unroll
  for (int rr = 0; rr < 4; ++rr) {
    pacc[w][g * 4 + rr][qq] = a0[rr];
    pacc[w][g * 4 + rr][qq + 16] = a1[rr];
  }
  __syncthreads();

  if (t < 512) {
    int qo = t >> 5, dd = t & 31;
    float sum = 0.f, st = 0.f;
#pragma unroll
    for (int wv = 0; wv < 16; ++wv) {
      sum += pacc[wv][qo][dd];
      st += wredS[wv][qo];
    }
    ctxb[((size_t)b * Q_ + qt * 16 + qo) * D_ + h * HD_ + dd] = f16bits(sum / st);
  }
}

// ---------- out projection: out = ctxb(f16) @ Wo^T + bo (fp32 out)
__global__ __launch_bounds__(256) void gemm_o(const unsigned short* __restrict__ A,
                                              const unsigned short* __restrict__ WoS,
                                              const float* __restrict__ bias,
                                              float* __restrict__ out) {
  int nt = blockIdx.x & 3, mt = blockIdx.x >> 2;
  int t = threadIdx.x, w = t >> 6, l = t & 63;
  int m0 = mt * 16;
  int r = l & 15, g = l >> 4;
  const unsigned short* arow = A + (size_t)(m0 + r) * D_;
  int tB = nt * 4 + w;
  f16x8 af[8], bf[8];
#pragma unroll
  for (int s = 0; s < 8; ++s) {
    af[s] = *(const f16x8*)(arow + s * 32 + g * 8);
    bf[s] = ((const f16x8*)WoS)[(tB * 8 + s) * 64 + l];
  }
  f32x4 acc = {0.f, 0.f, 0.f, 0.f};
#pragma unroll
  for (int s = 0; s < 8; ++s)
    acc = __builtin_amdgcn_mfma_f32_16x16x32_f16(af[s], bf[s], acc, 0, 0, 0);
  int n = nt * 64 + w * 16 + r;
  float bb = bias[n];
#pragma unroll
  for (int rr = 0; rr < 4; ++rr)
    out[(size_t)(m0 + g * 4 + rr) * D_ + n] = acc[rr] + bb;
}

extern "C" void kernel_launch(void* const* d_in, const int* in_sizes, int n_in,
                              void* d_out, int out_size, void* d_ws, size_t ws_size,
                              hipStream_t stream) {
  const float* ent  = (const float*)d_in[0];
  const float* img  = (const float*)d_in[1];
  const float* rd   = (const float*)d_in[2];
  const float* Wq   = (const float*)d_in[3];
  const float* bq   = (const float*)d_in[4];
  const float* Wkv  = (const float*)d_in[5];
  const float* bkv  = (const float*)d_in[6];
  const float* W1   = (const float*)d_in[7];
  const float* b1   = (const float*)d_in[8];
  const float* W2   = (const float*)d_in[9];
  const float* b2   = (const float*)d_in[10];
  const float* Wo   = (const float*)d_in[11];
  const float* bo   = (const float*)d_in[12];
  float* out = (float*)d_out;
  (void)b2;  // cancels in softmax (constant per row)

  char* ws = (char*)d_ws;
  unsigned short* kps   = (unsigned short*)(ws + 0);         // 2,097,152 f16 swizzled K
  unsigned short* vt    = (unsigned short*)(ws + 2097152);   // 2,097,152 f16 [b][h][dd][k]
  unsigned short* cpb4  = (unsigned short*)(ws + 4194304);   // 16,777,216 f16 cpb fragments
  unsigned short* ctxb  = (unsigned short*)(ws + 20971520);  //   262,144 f16 [b][q][c]
  unsigned short* qpf   = (unsigned short*)(ws + 21233664);  //   262,144 f16 q fragments
  unsigned short* entS  = (unsigned short*)(ws + 21495808);  //   262,144 f16 frag
  unsigned short* imgS  = (unsigned short*)(ws + 21757952);  // 2,097,152 f16 frag
  unsigned short* WqS   = (unsigned short*)(ws + 23855104);  //   131,072 f16 frag
  unsigned short* WkvS  = (unsigned short*)(ws + 23986176);  //   262,144 f16 frag
  unsigned short* WoS   = (unsigned short*)(ws + 24248320);  //   131,072 f16 frag

  prep<<<dim3(352), dim3(512), 0, stream>>>(ent, img, Wq, Wkv, Wo,
                                            entS, imgS, WqS, WkvS, WoS);
  mid<<<dim3(2048 + 64 + 1024), dim3(256), 0, stream>>>(
      rd, W1, b1, W2, cpb4, entS, WqS, bq, qpf, imgS, WkvS, bkv, kps, vt);
  attn<<<dim3(B_ * H_ * 16), dim3(1024), 0, stream>>>(qpf, kps, cpb4, vt, ctxb);
  gemm_o<<<dim3(128), dim3(256), 0, stream>>>(ctxb, WoS, bo, out);
}